// Round 13
// baseline (84.269 us; speedup 1.0000x reference)
//
#include <hip/hip_runtime.h>
#include <math.h>

// MaxYager2d: out[b,f,si,sj] = max(0, 1 - (min_{c,kh,kw} A[b,c,si+kh,sj+kw] + BW[c,kh,kw,f])^(2/3))
// A = (1-x)^1.5, BW = (1-w)^1.5. Max over J commutes with the monotone-
// decreasing Yager combine -> tropical min-plus 3x3 conv.
//
// r13 = r9 (16.3 us anchor: single dispatch, grid 256 x 1024 thr, one
// (b,row) per block, 16 waves x 2 f) + two LDS-layout fixes ONLY:
//  1) A packed half4 (4ch/slot): compute A-reads 96 -> ~72 instrs/wave,
//     stage writes b64 (2-way = free).
//  2) ldsB padded to 40 halfs/row: B-stage write f-stride 720B = 180 dw,
//     gcd(180,32)=4 -> 8 banks (was 2 banks / 16-way, 1.13M confl cycles).
//     b128 read alignment preserved (720/80/16 all = 0 mod 16).
// Arithmetic value-set identical -> absmax 0.00390625 unchanged.

#define CIN  32
#define FOUT 32
#define KS   3
#define HW   66   // input spatial
#define SS   64   // output spatial
#define NB   4    // batch
#define BPAD 40   // padded B row

typedef _Float16 half2_t __attribute__((ext_vector_type(2)));
typedef _Float16 half4_t __attribute__((ext_vector_type(4)));   // 8 B
typedef _Float16 half8_t __attribute__((ext_vector_type(8)));   // 16 B

static __device__ __forceinline__ half2_t mk2(float a, float b) {
    half2_t r; r.x = (_Float16)a; r.y = (_Float16)b; return r;
}
static __device__ __forceinline__ _Float16 yg(float v) {
    float t = 1.0f - v;
    return (_Float16)(t * sqrtf(t));   // (1-v)^1.5
}

union bvec {
    half8_t v8;
    half2_t v2[4];
};

__global__ __launch_bounds__(1024) void yager_one(
    const float* __restrict__ x, const float* __restrict__ w,
    float* __restrict__ out)
{
    __shared__ __align__(16) half4_t  ldsA[8][KS][68];      // 13.1 KB [slot][kr][col]
    __shared__ __align__(16) _Float16 ldsB[FOUT][9][BPAD];  // 23.0 KB [f][t][c] padded

    const int tid = threadIdx.x;
    const int row = blockIdx.x & (SS - 1);
    const int b   = blockIdx.x >> 6;

    // --- stage B: coalesced w reads (9216 = 9/thread), transform, scatter.
    // i: f = i&31, j = i>>5 -> c = j/9, t = j%9. Write f-stride 720 B.
#pragma unroll
    for (int k = 0; k < 9; ++k) {
        int i  = tid + k * 1024;
        float v = w[i];
        int f  = i & 31;
        int j  = i >> 5;
        int c  = j / 9;
        int t  = j - 9 * c;
        ldsB[f][t][c] = yg(v);
    }

    // --- stage A: slot s = channels 4s..4s+3 as half4 (b64 writes, free).
    for (int i = tid; i < 8 * KS * HW; i += 1024) {
        int s   = i / (KS * HW);
        int r   = i - s * (KS * HW);
        int kr  = r / HW;
        int col = r - kr * HW;
        const float* xp = x + (((size_t)b * CIN + 4 * s) * HW + row + kr) * HW + col;
        half4_t v;
        v.x = yg(xp[0]);
        v.y = yg(xp[(size_t)HW * HW]);
        v.z = yg(xp[(size_t)2 * HW * HW]);
        v.w = yg(xp[(size_t)3 * HW * HW]);
        ldsA[s][kr][col] = v;
    }
    __syncthreads();

    const int lane = tid & 63;                                  // output col
    const int wv   = __builtin_amdgcn_readfirstlane(tid >> 6);  // 0..15
    const int f0   = wv * 2;                                    // f pair

    // two accumulators per f (h parity) to shorten min dep-chains
    half2_t M0a = mk2(4.0f, 4.0f), M0b = M0a, M1a = M0a, M1b = M0a;

#pragma unroll
    for (int q = 0; q < 4; ++q) {       // channels 8q..8q+7
        bvec bq0[9], bq1[9];
#pragma unroll
        for (int t = 0; t < 9; ++t) {   // wave-uniform broadcast b128 (free)
            bq0[t].v8 = *(const half8_t*)&ldsB[f0][t][8 * q];
            bq1[t].v8 = *(const half8_t*)&ldsB[f0 + 1][t][8 * q];
        }
#pragma unroll
        for (int h = 0; h < 2; ++h) {   // A slot s = 2q+h
            const int s = 2 * q + h;
            half4_t a[KS][KS];
#pragma unroll
            for (int kr = 0; kr < KS; ++kr)
#pragma unroll
                for (int kw = 0; kw < KS; ++kw)
                    a[kr][kw] = ldsA[s][kr][lane + kw];
#pragma unroll
            for (int t = 0; t < 9; ++t) {
                half4_t av = a[t / 3][t % 3];
                half2_t alo = { av.x, av.y };       // ch pair 4q+2h
                half2_t ahi = { av.z, av.w };       // ch pair 4q+2h+1
                half2_t s0l = alo + bq0[t].v2[2 * h];
                half2_t s0h = ahi + bq0[t].v2[2 * h + 1];
                half2_t s1l = alo + bq1[t].v2[2 * h];
                half2_t s1h = ahi + bq1[t].v2[2 * h + 1];
                if (h) { M0b = __builtin_elementwise_min(M0b, s0l);
                         M0b = __builtin_elementwise_min(M0b, s0h);
                         M1b = __builtin_elementwise_min(M1b, s1l);
                         M1b = __builtin_elementwise_min(M1b, s1h); }
                else   { M0a = __builtin_elementwise_min(M0a, s0l);
                         M0a = __builtin_elementwise_min(M0a, s0h);
                         M1a = __builtin_elementwise_min(M1a, s1l);
                         M1a = __builtin_elementwise_min(M1a, s1h); }
            }
        }
    }

    half2_t M0 = __builtin_elementwise_min(M0a, M0b);
    half2_t M1 = __builtin_elementwise_min(M1a, M1b);
    float m0 = fminf((float)M0.x, (float)M0.y);
    float m1 = fminf((float)M1.x, (float)M1.y);
    float r0 = 1.0f - exp2f(0.6666666667f * log2f(m0));
    float r1 = 1.0f - exp2f(0.6666666667f * log2f(m1));
    float* op = out + (((size_t)b * FOUT + f0) * SS + row) * SS + lane;
    op[0]       = fmaxf(r0, 0.0f);
    op[SS * SS] = fmaxf(r1, 0.0f);
}

extern "C" void kernel_launch(void* const* d_in, const int* in_sizes, int n_in,
                              void* d_out, int out_size, void* d_ws, size_t ws_size,
                              hipStream_t stream)
{
    const float* x = (const float*)d_in[0];   // [4,32,66,66] f32
    const float* w = (const float*)d_in[1];   // [288,32] f32
    float* out = (float*)d_out;               // [4,32,64,64] f32
    (void)d_ws; (void)ws_size;

    yager_one<<<NB * SS, 1024, 0, stream>>>(x, w, out);
}

// Round 14
// 14.356 us; speedup vs baseline: 5.8699x; 5.8699x over previous
//
#include <hip/hip_runtime.h>
#include <math.h>

// MaxYager2d: out[b,f,si,sj] = max(0, 1 - (min_{c,kh,kw} A[b,c,si+kh,sj+kw] + BW[c,kh,kw,f])^(2/3))
// A = (1-x)^1.5, BW = (1-w)^1.5. Max over J commutes with the monotone-
// decreasing Yager combine -> tropical min-plus 3x3 conv.
//
// r14: raise outputs-per-LDS-instruction (the binding pipe all session):
//  - ROW-PAIR per lane: lane computes output rows (2p, 2p+1) -> same B
//    broadcast serves both rows (B instrs/output halved); A window rows
//    0..3 serve both (A instrs/output -33%).
//  - A packed half8 (8 ch/slot): 1 b128 = 8 channels' tap.
//  - per wave: 48 A-b128 + 72 B-b128 for 256 outputs (r9: 168 for 128).
//  - B LDS row stride 148 half2 (592 B): 16 f-lanes spread 8 banks (2-way,
//    free) on stage scatter; b128 reads stay 16B-aligned; broadcast reads.
//  - live regs ~55 (a-tile 24 + B 8 + acc 8) -> no spill (r10/r13 lesson);
//    __launch_bounds__(512,2) caps occupancy demand, not registers.
// Single dispatch, grid 256 = b(4) x pair(32) x fhalf(2), 512 thr (8 waves,
// wave wv -> local f pair 2wv,2wv+1). Same value set -> absmax 0.00390625.

#define CIN  32
#define FOUT 32
#define KS   3
#define HW   66
#define SS   64
#define NB   4

typedef _Float16 half2_t __attribute__((ext_vector_type(2)));
typedef _Float16 half8_t __attribute__((ext_vector_type(8)));

static __device__ __forceinline__ _Float16 yg(float v) {
    float t = 1.0f - v;
    return (_Float16)(t * sqrtf(t));   // (1-v)^1.5
}

union bv8 {
    half8_t v8;
    half2_t v2[4];
};

__global__ __launch_bounds__(512, 2) void yager_one(
    const float* __restrict__ x, const float* __restrict__ w,
    float* __restrict__ out)
{
    __shared__ __align__(16) half8_t ldsA[4][4][68];   // 17.4 KB [q(8ch)][row][col]
    __shared__ __align__(16) half2_t ldsB[16][148];    // 9.5 KB  [fi][t*16 + 4q + c4] (pad 4)

    const int tid  = threadIdx.x;
    const int fh   = blockIdx.x & 1;          // f-half
    const int pair = (blockIdx.x >> 1) & 31;  // output row pair
    const int b    = blockIdx.x >> 6;

    // --- stage B (this block's 16 f): 4608 elems, 9/thread, coalesced reads
    // (16 consecutive f32 per j). Write: fi-lanes spread 8 banks (2-way).
#pragma unroll
    for (int k = 0; k < 9; ++k) {
        int i  = tid + k * 512;
        int fi = i & 15;
        int j  = i >> 4;                      // c*9 + t, 0..287
        int c  = j / 9;
        int t  = j - 9 * c;
        float v = w[j * FOUT + fh * 16 + fi];
        ((_Float16*)ldsB)[fi * 296 + t * 32 + c] = yg(v);
    }

    // --- stage A: input rows 2p..2p+3, channels as half8 slots q=0..3.
    // 1056 half8s; 8 strided yg-reads each, col-consecutive -> coalesced.
    for (int i = tid; i < 4 * 4 * HW; i += 512) {
        int q   = i / (4 * HW);
        int r   = i - q * (4 * HW);
        int row = r / HW;
        int col = r - row * HW;
        const float* xp = x + (((size_t)b * CIN + 8 * q) * HW + 2 * pair + row) * HW + col;
        half8_t v;
#pragma unroll
        for (int k = 0; k < 8; ++k)
            v[k] = yg(xp[(size_t)k * HW * HW]);
        ldsA[q][row][col] = v;
    }
    __syncthreads();

    const int lane = tid & 63;                                  // output col
    const int wv   = __builtin_amdgcn_readfirstlane(tid >> 6);  // 0..7
    const int f0   = wv * 2;                                    // local f pair

    // acc[r][f][parity] as 8 independent half2 min-chains
    half2_t acc[2][2][2];
#pragma unroll
    for (int r = 0; r < 2; ++r)
#pragma unroll
        for (int f = 0; f < 2; ++f)
#pragma unroll
            for (int p = 0; p < 2; ++p) {
                half2_t z; z.x = (_Float16)4.0f; z.y = (_Float16)4.0f;
                acc[r][f][p] = z;
            }

#pragma unroll
    for (int q = 0; q < 4; ++q) {
        // A tile: 4 LDS rows x 3 kw, serves both output rows
        half8_t a[4][KS];
#pragma unroll
        for (int rr = 0; rr < 4; ++rr)
#pragma unroll
            for (int kw = 0; kw < KS; ++kw)
                a[rr][kw] = ldsA[q][rr][lane + kw];
#pragma unroll
        for (int t = 0; t < 9; ++t) {
            const int kr = t / 3, kw = t % 3;
            bv8 B0, B1;                       // wave-uniform broadcast b128
            B0.v8 = *(const half8_t*)&ldsB[f0][t * 16 + 4 * q];
            B1.v8 = *(const half8_t*)&ldsB[f0 + 1][t * 16 + 4 * q];
#pragma unroll
            for (int r = 0; r < 2; ++r) {
                bv8 av; av.v8 = a[kr + r][kw];
#pragma unroll
                for (int c4 = 0; c4 < 4; ++c4) {
                    half2_t s0 = av.v2[c4] + B0.v2[c4];
                    half2_t s1 = av.v2[c4] + B1.v2[c4];
                    acc[r][0][c4 & 1] = __builtin_elementwise_min(acc[r][0][c4 & 1], s0);
                    acc[r][1][c4 & 1] = __builtin_elementwise_min(acc[r][1][c4 & 1], s1);
                }
            }
        }
    }

#pragma unroll
    for (int r = 0; r < 2; ++r)
#pragma unroll
        for (int f = 0; f < 2; ++f) {
            half2_t M = __builtin_elementwise_min(acc[r][f][0], acc[r][f][1]);
            float m = fminf((float)M.x, (float)M.y);
            float rv = 1.0f - exp2f(0.6666666667f * log2f(m));
            out[(((size_t)b * FOUT + fh * 16 + f0 + f) * SS + 2 * pair + r) * SS + lane]
                = fmaxf(rv, 0.0f);
        }
}

extern "C" void kernel_launch(void* const* d_in, const int* in_sizes, int n_in,
                              void* d_out, int out_size, void* d_ws, size_t ws_size,
                              hipStream_t stream)
{
    const float* x = (const float*)d_in[0];   // [4,32,66,66] f32
    const float* w = (const float*)d_in[1];   // [288,32] f32
    float* out = (float*)d_out;               // [4,32,64,64] f32
    (void)d_ws; (void)ws_size;

    yager_one<<<NB * 32 * 2, 512, 0, stream>>>(x, w, out);
}